// Round 1
// baseline (3067.935 us; speedup 1.0000x reference)
//
#include <hip/hip_runtime.h>
#include <hip/hip_bf16.h>
#include <math.h>

namespace {
constexpr int T_TOK = 4096;   // B*S
constexpr int H_DIM = 2048;
constexpr int F_DIM = 1024;
constexpr int E_NUM = 16;

constexpr int BM = 64;
constexpr int BN = 64;
constexpr int BK = 16;
}

// ---------------------------------------------------------------------------
// Router: logits = x @ w_gate, softmax fp32, top-4, renormalize.
// One block per token. Also zeroes the token's output row and appends
// (token, weight) to the per-expert lists.
// ---------------------------------------------------------------------------
__global__ __launch_bounds__(256) void router_kernel(
    const float* __restrict__ x,       // [T, H]
    const float* __restrict__ wg,      // [H, E]
    float* __restrict__ out,           // [T, H]  (zeroed here)
    float* __restrict__ logits,        // [T, E]
    int* __restrict__ cnt,             // [E]
    int* __restrict__ ptok,            // [E, T]
    float* __restrict__ pw)            // [E, T]
{
  const int t = blockIdx.x;
  const int tid = threadIdx.x;

  // zero this token's output row (harness poisons d_out with 0xAA)
  float4 z = {0.f, 0.f, 0.f, 0.f};
  float4* orow = (float4*)(out + (size_t)t * H_DIM);
  for (int i = tid; i < H_DIM / 4; i += 256) orow[i] = z;

  // partial dot products: each thread owns 8 consecutive h
  float acc[E_NUM];
#pragma unroll
  for (int e = 0; e < E_NUM; ++e) acc[e] = 0.f;
  const float* xrow = x + (size_t)t * H_DIM;
#pragma unroll
  for (int hh = 0; hh < 8; ++hh) {
    int h = tid * 8 + hh;
    float xv = xrow[h];
    const float4* wrow = (const float4*)(wg + (size_t)h * E_NUM);
#pragma unroll
    for (int q = 0; q < 4; ++q) {
      float4 w4 = wrow[q];
      acc[q * 4 + 0] = fmaf(xv, w4.x, acc[q * 4 + 0]);
      acc[q * 4 + 1] = fmaf(xv, w4.y, acc[q * 4 + 1]);
      acc[q * 4 + 2] = fmaf(xv, w4.z, acc[q * 4 + 2]);
      acc[q * 4 + 3] = fmaf(xv, w4.w, acc[q * 4 + 3]);
    }
  }

  // wave(64) shuffle reduce, then cross-wave via LDS
#pragma unroll
  for (int e = 0; e < E_NUM; ++e) {
    for (int o = 32; o > 0; o >>= 1) acc[e] += __shfl_down(acc[e], o, 64);
  }
  __shared__ float red[4][E_NUM];
  __shared__ float lg[E_NUM];
  int wave = tid >> 6, lane = tid & 63;
  if (lane == 0) {
#pragma unroll
    for (int e = 0; e < E_NUM; ++e) red[wave][e] = acc[e];
  }
  __syncthreads();
  if (tid < E_NUM) {
    float v = red[0][tid] + red[1][tid] + red[2][tid] + red[3][tid];
    lg[tid] = v;
    logits[(size_t)t * E_NUM + tid] = v;
  }
  __syncthreads();

  if (tid == 0) {
    float l[E_NUM];
#pragma unroll
    for (int e = 0; e < E_NUM; ++e) l[e] = lg[e];
    float m = l[0];
#pragma unroll
    for (int e = 1; e < E_NUM; ++e) m = fmaxf(m, l[e]);
    float ex[E_NUM];
#pragma unroll
    for (int e = 0; e < E_NUM; ++e) ex[e] = __expf(l[e] - m);
    // top-4 by logit (ties -> lowest index, matches lax.top_k)
    bool used[E_NUM] = {};
    int ids[4];
    float vs[4];
    float s4 = 0.f;
    for (int k = 0; k < 4; ++k) {
      int b = 0;
      float bv = -3.4e38f;
      for (int e = 0; e < E_NUM; ++e)
        if (!used[e] && l[e] > bv) { bv = l[e]; b = e; }
      used[b] = true;
      ids[k] = b;
      vs[k] = ex[b];
      s4 += ex[b];
    }
    for (int k = 0; k < 4; ++k) {
      float w = vs[k] / s4;
      int slot = atomicAdd(&cnt[ids[k]], 1);
      ptok[ids[k] * T_TOK + slot] = t;
      pw[ids[k] * T_TOK + slot] = w;
    }
  }
}

__global__ void prefix_kernel(const int* __restrict__ cnt, int* __restrict__ off) {
  if (threadIdx.x == 0) {
    int s = 0;
    for (int e = 0; e < E_NUM; ++e) { off[e] = s; s += cnt[e]; }
  }
}

// ---------------------------------------------------------------------------
// Gate+Up GEMM: for expert e, gathered token rows [Me, H] x Wg/Wu[e] [H, F]
// -> h_act = silu(g) * u, written compactly at row off[e]+m.
// grid = E * (T/BM) * (F/BN); empty tiles exit.
// ---------------------------------------------------------------------------
__global__ __launch_bounds__(256) void gateup_kernel(
    const float* __restrict__ x,    // [T, H]
    const float* __restrict__ Wg,   // [E, H, F]
    const float* __restrict__ Wu,   // [E, H, F]
    const int* __restrict__ cnt,
    const int* __restrict__ off,
    const int* __restrict__ ptok,   // [E, T]
    float* __restrict__ hact)       // [4T + pad, F]
{
  const int bx = blockIdx.x;
  const int e = bx >> 10;           // / (64 * 16)
  const int mt = (bx >> 4) & 63;
  const int nt = bx & 15;
  const int me = cnt[e];
  const int m0 = mt * BM;
  if (m0 >= me) return;
  const int f0 = nt * BN;
  const int tid = threadIdx.x;

  __shared__ float As[BK][BM + 4];
  __shared__ float Bg[BK][BN + 4];
  __shared__ float Bu[BK][BN + 4];
  __shared__ int toks[BM];

  if (tid < BM) {
    int m = m0 + tid;
    toks[tid] = ptok[e * T_TOK + ((m < me) ? m : m0)];
  }
  __syncthreads();

  const int tx = tid & 15, ty = tid >> 4;
  const int lm = tid >> 2, lk4 = (tid & 3) * 4;
  const int wk = tid >> 4, wf4 = (tid & 15) * 4;

  const float* xptr = x + (size_t)toks[lm] * H_DIM + lk4;
  const float* wg_base = Wg + (size_t)e * H_DIM * F_DIM + f0 + wf4;
  const float* wu_base = Wu + (size_t)e * H_DIM * F_DIM + f0 + wf4;

  float accg[4][4] = {};
  float accu[4][4] = {};

  for (int h0 = 0; h0 < H_DIM; h0 += BK) {
    float4 av = *(const float4*)(xptr + h0);
    float4 gv = *(const float4*)(wg_base + (size_t)(h0 + wk) * F_DIM);
    float4 uv = *(const float4*)(wu_base + (size_t)(h0 + wk) * F_DIM);
    __syncthreads();  // previous iter's compute done
    As[lk4 + 0][lm] = av.x;
    As[lk4 + 1][lm] = av.y;
    As[lk4 + 2][lm] = av.z;
    As[lk4 + 3][lm] = av.w;
    *(float4*)&Bg[wk][wf4] = gv;
    *(float4*)&Bu[wk][wf4] = uv;
    __syncthreads();
#pragma unroll
    for (int k = 0; k < BK; ++k) {
      const float4 a = *(const float4*)&As[k][ty * 4];
      const float4 g4 = *(const float4*)&Bg[k][tx * 4];
      const float4 u4 = *(const float4*)&Bu[k][tx * 4];
      const float am[4] = {a.x, a.y, a.z, a.w};
      const float gn[4] = {g4.x, g4.y, g4.z, g4.w};
      const float un[4] = {u4.x, u4.y, u4.z, u4.w};
#pragma unroll
      for (int i = 0; i < 4; ++i)
#pragma unroll
        for (int j = 0; j < 4; ++j) {
          accg[i][j] = fmaf(am[i], gn[j], accg[i][j]);
          accu[i][j] = fmaf(am[i], un[j], accu[i][j]);
        }
    }
  }

  const int off_e = off[e];
#pragma unroll
  for (int i = 0; i < 4; ++i) {
    int m = m0 + ty * 4 + i;
    if (m < me) {
      float4 o;
      float g, u;
      g = accg[i][0]; u = accu[i][0]; o.x = g * u / (1.f + __expf(-g));
      g = accg[i][1]; u = accu[i][1]; o.y = g * u / (1.f + __expf(-g));
      g = accg[i][2]; u = accu[i][2]; o.z = g * u / (1.f + __expf(-g));
      g = accg[i][3]; u = accu[i][3]; o.w = g * u / (1.f + __expf(-g));
      *(float4*)(hact + (size_t)(off_e + m) * F_DIM + f0 + tx * 4) = o;
    }
  }
}

// ---------------------------------------------------------------------------
// Down GEMM: h_act [Me, F] x Wd[e] [F, H] -> atomicAdd(w * acc) into out.
// grid = E * (T/BM) * (H/BN)
// ---------------------------------------------------------------------------
__global__ __launch_bounds__(256) void down_kernel(
    const float* __restrict__ hact,  // [4T + pad, F]
    const float* __restrict__ Wd,    // [E, F, H]
    const int* __restrict__ cnt,
    const int* __restrict__ off,
    const int* __restrict__ ptok,
    const float* __restrict__ pw,
    float* __restrict__ out)         // [T, H] pre-zeroed
{
  const int bx = blockIdx.x;
  const int e = bx >> 11;            // / (64 * 32)
  const int mt = (bx >> 5) & 63;
  const int nt = bx & 31;
  const int me = cnt[e];
  const int m0 = mt * BM;
  if (m0 >= me) return;
  const int h0 = nt * BN;
  const int tid = threadIdx.x;

  __shared__ float Hs[BK][BM + 4];
  __shared__ float Ws[BK][BN + 4];
  __shared__ int toks[BM];
  __shared__ float tws[BM];

  if (tid < BM) {
    int m = m0 + tid;
    toks[tid] = (m < me) ? ptok[e * T_TOK + m] : 0;
    tws[tid] = (m < me) ? pw[e * T_TOK + m] : 0.f;
  }
  __syncthreads();

  const int tx = tid & 15, ty = tid >> 4;
  const int lm = tid >> 2, lk4 = (tid & 3) * 4;
  const int wk = tid >> 4, wf4 = (tid & 15) * 4;

  const int off_e = off[e];
  const float* hrow = hact + (size_t)(off_e + m0 + lm) * F_DIM + lk4;
  const float* wd_base = Wd + (size_t)e * F_DIM * H_DIM + h0 + wf4;

  float acc[4][4] = {};

  for (int f0 = 0; f0 < F_DIM; f0 += BK) {
    float4 hv = *(const float4*)(hrow + f0);
    float4 wv = *(const float4*)(wd_base + (size_t)(f0 + wk) * H_DIM);
    __syncthreads();
    Hs[lk4 + 0][lm] = hv.x;
    Hs[lk4 + 1][lm] = hv.y;
    Hs[lk4 + 2][lm] = hv.z;
    Hs[lk4 + 3][lm] = hv.w;
    *(float4*)&Ws[wk][wf4] = wv;
    __syncthreads();
#pragma unroll
    for (int k = 0; k < BK; ++k) {
      const float4 a = *(const float4*)&Hs[k][ty * 4];
      const float4 b = *(const float4*)&Ws[k][tx * 4];
      const float am[4] = {a.x, a.y, a.z, a.w};
      const float bn[4] = {b.x, b.y, b.z, b.w};
#pragma unroll
      for (int i = 0; i < 4; ++i)
#pragma unroll
        for (int j = 0; j < 4; ++j)
          acc[i][j] = fmaf(am[i], bn[j], acc[i][j]);
    }
  }

#pragma unroll
  for (int i = 0; i < 4; ++i) {
    int m = m0 + ty * 4 + i;
    if (m < me) {
      int t = toks[ty * 4 + i];
      float w = tws[ty * 4 + i];
      float* orow = out + (size_t)t * H_DIM + h0 + tx * 4;
      atomicAdd(orow + 0, w * acc[i][0]);
      atomicAdd(orow + 1, w * acc[i][1]);
      atomicAdd(orow + 2, w * acc[i][2]);
      atomicAdd(orow + 3, w * acc[i][3]);
    }
  }
}

// ---------------------------------------------------------------------------
extern "C" void kernel_launch(void* const* d_in, const int* in_sizes, int n_in,
                              void* d_out, int out_size, void* d_ws, size_t ws_size,
                              hipStream_t stream) {
  const float* x = (const float*)d_in[0];   // hidden_states [B,S,H]
  const float* wg = (const float*)d_in[1];  // w_gate [H,E]
  const float* Wg = (const float*)d_in[2];  // [E,H,F]
  const float* Wu = (const float*)d_in[3];  // [E,H,F]
  const float* Wd = (const float*)d_in[4];  // [E,F,H]

  float* out = (float*)d_out;                       // [T,H]
  float* logits = out + (size_t)T_TOK * H_DIM;      // [T,E]

  // workspace layout (re-poisoned 0xAA before each call)
  char* wsb = (char*)d_ws;
  int* cnt = (int*)wsb;                     // [E]
  int* off = cnt + E_NUM;                   // [E]
  int* ptok = off + E_NUM;                  // [E, T]
  float* pw = (float*)(ptok + E_NUM * T_TOK);  // [E, T]
  float* hact = pw + E_NUM * T_TOK;         // [4T + 64, F] = ~64.3 MB

  hipMemsetAsync(cnt, 0, E_NUM * sizeof(int), stream);
  hipLaunchKernelGGL(router_kernel, dim3(T_TOK), dim3(256), 0, stream,
                     x, wg, out, logits, cnt, ptok, pw);
  hipLaunchKernelGGL(prefix_kernel, dim3(1), dim3(64), 0, stream, cnt, off);
  hipLaunchKernelGGL(gateup_kernel, dim3(E_NUM * 64 * 16), dim3(256), 0, stream,
                     x, Wg, Wu, cnt, off, ptok, hact);
  hipLaunchKernelGGL(down_kernel, dim3(E_NUM * 64 * 32), dim3(256), 0, stream,
                     hact, Wd, cnt, off, ptok, pw, out);
}

// Round 3
// 1020.280 us; speedup vs baseline: 3.0070x; 3.0070x over previous
//
#include <hip/hip_runtime.h>
#include <hip/hip_bf16.h>
#include <math.h>

namespace {
constexpr int T_TOK = 4096;   // B*S
constexpr int H_DIM = 2048;
constexpr int F_DIM = 1024;
constexpr int E_NUM = 16;
}

typedef __bf16 bf16;
typedef __attribute__((ext_vector_type(8))) __bf16 bf16x8;
typedef __attribute__((ext_vector_type(4))) __bf16 bf16x4;
typedef __attribute__((ext_vector_type(4))) float f32x4;

// ---------------------------------------------------------------------------
// Router: logits = x @ w_gate (fp32), softmax fp32, top-4, renormalize.
// One block per token. Zeroes the token's out row, appends to expert lists.
// Validated in round 0.
// ---------------------------------------------------------------------------
__global__ __launch_bounds__(256) void router_kernel(
    const float* __restrict__ x, const float* __restrict__ wg,
    float* __restrict__ out, float* __restrict__ logits,
    int* __restrict__ cnt, int* __restrict__ ptok, float* __restrict__ pw)
{
  const int t = blockIdx.x;
  const int tid = threadIdx.x;

  float4 z = {0.f, 0.f, 0.f, 0.f};
  float4* orow = (float4*)(out + (size_t)t * H_DIM);
  for (int i = tid; i < H_DIM / 4; i += 256) orow[i] = z;

  float acc[E_NUM];
#pragma unroll
  for (int e = 0; e < E_NUM; ++e) acc[e] = 0.f;
  const float* xrow = x + (size_t)t * H_DIM;
#pragma unroll
  for (int hh = 0; hh < 8; ++hh) {
    int h = tid * 8 + hh;
    float xv = xrow[h];
    const float4* wrow = (const float4*)(wg + (size_t)h * E_NUM);
#pragma unroll
    for (int q = 0; q < 4; ++q) {
      float4 w4 = wrow[q];
      acc[q * 4 + 0] = fmaf(xv, w4.x, acc[q * 4 + 0]);
      acc[q * 4 + 1] = fmaf(xv, w4.y, acc[q * 4 + 1]);
      acc[q * 4 + 2] = fmaf(xv, w4.z, acc[q * 4 + 2]);
      acc[q * 4 + 3] = fmaf(xv, w4.w, acc[q * 4 + 3]);
    }
  }

#pragma unroll
  for (int e = 0; e < E_NUM; ++e) {
    for (int o = 32; o > 0; o >>= 1) acc[e] += __shfl_down(acc[e], o, 64);
  }
  __shared__ float red[4][E_NUM];
  __shared__ float lg[E_NUM];
  int wave = tid >> 6, lane = tid & 63;
  if (lane == 0) {
#pragma unroll
    for (int e = 0; e < E_NUM; ++e) red[wave][e] = acc[e];
  }
  __syncthreads();
  if (tid < E_NUM) {
    float v = red[0][tid] + red[1][tid] + red[2][tid] + red[3][tid];
    lg[tid] = v;
    logits[(size_t)t * E_NUM + tid] = v;
  }
  __syncthreads();

  if (tid == 0) {
    float l[E_NUM];
#pragma unroll
    for (int e = 0; e < E_NUM; ++e) l[e] = lg[e];
    float m = l[0];
#pragma unroll
    for (int e = 1; e < E_NUM; ++e) m = fmaxf(m, l[e]);
    float ex[E_NUM];
#pragma unroll
    for (int e = 0; e < E_NUM; ++e) ex[e] = __expf(l[e] - m);
    bool used[E_NUM] = {};
    int ids[4]; float vs[4]; float s4 = 0.f;
    for (int k = 0; k < 4; ++k) {
      int b = 0; float bv = -3.4e38f;
      for (int e = 0; e < E_NUM; ++e)
        if (!used[e] && l[e] > bv) { bv = l[e]; b = e; }
      used[b] = true; ids[k] = b; vs[k] = ex[b]; s4 += ex[b];
    }
    for (int k = 0; k < 4; ++k) {
      float w = vs[k] / s4;
      int slot = atomicAdd(&cnt[ids[k]], 1);
      ptok[ids[k] * T_TOK + slot] = t;
      pw[ids[k] * T_TOK + slot] = w;
    }
  }
}

__global__ void prefix_kernel(const int* __restrict__ cnt, int* __restrict__ off) {
  if (threadIdx.x == 0) {
    int s = 0;
    for (int e = 0; e < E_NUM; ++e) { off[e] = s; s += cnt[e]; }
  }
}

// fp32 -> bf16, vectorized
__global__ __launch_bounds__(256) void convert_x_kernel(
    const float* __restrict__ in, bf16* __restrict__ out, int n4)
{
  int i = blockIdx.x * 256 + threadIdx.x;
  if (i < n4) {
    float4 v = ((const float4*)in)[i];
    bf16x4 o = {(bf16)v.x, (bf16)v.y, (bf16)v.z, (bf16)v.w};
    ((bf16x4*)out)[i] = o;
  }
}

// ---------------------------------------------------------------------------
// Gate+Up MFMA GEMM. A = gathered bf16 x rows via LDS; B = fp32 weights read
// DIRECTLY from global in the MFMA fragment pattern (4 full 64B lines per
// load element), converted to bf16 in-register. No weight copies in ws.
// BM=128, BN=64 (both g and u at this f-block), BK=32, 4 waves (2x2).
// ---------------------------------------------------------------------------
__global__ __launch_bounds__(256) void gateup_mfma_kernel(
    const bf16* __restrict__ xb,   // [T, H]
    const float* __restrict__ Wg,  // [E, H, F]
    const float* __restrict__ Wu,  // [E, H, F]
    const int* __restrict__ cnt, const int* __restrict__ off,
    const int* __restrict__ ptok, bf16* __restrict__ hact)
{
  const int bx = blockIdx.x;
  const int e = bx >> 9;          // 32 mt * 16 nt
  const int mt = (bx >> 4) & 31;
  const int nt = bx & 15;
  const int me = cnt[e];
  const int m0 = mt * 128;
  if (m0 >= me) return;
  const int f0 = nt * 64;
  const int tid = threadIdx.x;

  __shared__ bf16 As[128][40];   // [m][k], pad 32->40 (2-way alias = free)
  __shared__ int toks[128];

  if (tid < 128) {
    int m = m0 + tid;
    toks[tid] = ptok[e * T_TOK + ((m < me) ? m : (me - 1))];
  }
  __syncthreads();

  const int ar1 = tid >> 2, ak = (tid & 3) * 8;
  const int ar2 = ar1 + 64;
  const bf16* apt1 = xb + (size_t)toks[ar1] * H_DIM + ak;
  const bf16* apt2 = xb + (size_t)toks[ar2] * H_DIM + ak;

  const int wave = tid >> 6, lane = tid & 63;
  const int wr = wave >> 1, wc = wave & 1;
  const int lrow = lane & 15;
  const int lkq = (lane >> 4) * 8;   // lane's k-base within BK=32

  // per-lane weight base: row lkq, col f0 + wc*32 + lrow
  const float* gp = Wg + (size_t)e * H_DIM * F_DIM + (size_t)lkq * F_DIM + f0 + wc * 32 + lrow;
  const float* up = Wu + (size_t)e * H_DIM * F_DIM + (size_t)lkq * F_DIM + f0 + wc * 32 + lrow;

  f32x4 accg[4][2] = {};
  f32x4 accu[4][2] = {};

  for (int h0 = 0; h0 < H_DIM; h0 += 32) {
    bf16x8 a1 = *(const bf16x8*)(apt1 + h0);
    bf16x8 a2 = *(const bf16x8*)(apt2 + h0);
    // B fragments straight from global fp32 (k stride = F_DIM floats)
    bf16x8 gf[2], uf[2];
#pragma unroll
    for (int c = 0; c < 2; ++c) {
      const float* gpc = gp + (size_t)h0 * F_DIM + c * 16;
      const float* upc = up + (size_t)h0 * F_DIM + c * 16;
#pragma unroll
      for (int i = 0; i < 8; ++i) {
        gf[c][i] = (bf16)gpc[(size_t)i * F_DIM];
        uf[c][i] = (bf16)upc[(size_t)i * F_DIM];
      }
    }
    __syncthreads();
    *(bf16x8*)&As[ar1][ak] = a1;
    *(bf16x8*)&As[ar2][ak] = a2;
    __syncthreads();
    bf16x8 af[4];
#pragma unroll
    for (int r = 0; r < 4; ++r)
      af[r] = *(const bf16x8*)&As[wr * 64 + r * 16 + lrow][lkq];
#pragma unroll
    for (int r = 0; r < 4; ++r)
#pragma unroll
      for (int c = 0; c < 2; ++c) {
        accg[r][c] = __builtin_amdgcn_mfma_f32_16x16x32_bf16(af[r], gf[c], accg[r][c], 0, 0, 0);
        accu[r][c] = __builtin_amdgcn_mfma_f32_16x16x32_bf16(af[r], uf[c], accu[r][c], 0, 0, 0);
      }
  }

  const int off_e = off[e];
#pragma unroll
  for (int r = 0; r < 4; ++r)
#pragma unroll
    for (int j = 0; j < 4; ++j) {
      int m = m0 + wr * 64 + r * 16 + (lane >> 4) * 4 + j;
      if (m < me) {
#pragma unroll
        for (int c = 0; c < 2; ++c) {
          float g = accg[r][c][j], u = accu[r][c][j];
          float h = g * u / (1.f + __expf(-g));
          hact[(size_t)(off_e + m) * F_DIM + f0 + wc * 32 + c * 16 + lrow] = (bf16)h;
        }
      }
    }
}

// ---------------------------------------------------------------------------
// Down MFMA GEMM: hact [me,F] bf16 x Wd[e] [F,H] fp32(direct) -> atomicAdd.
// BM=128, BN=128, BK=32, 4 waves (2x2).
// ---------------------------------------------------------------------------
__global__ __launch_bounds__(256) void down_mfma_kernel(
    const bf16* __restrict__ hact,  // [16512, F]
    const float* __restrict__ Wd,   // [E, F, H]
    const int* __restrict__ cnt, const int* __restrict__ off,
    const int* __restrict__ ptok, const float* __restrict__ pw,
    float* __restrict__ out)
{
  const int bx = blockIdx.x;
  const int e = bx >> 9;          // 32 mt * 16 nt
  const int mt = (bx >> 4) & 31;
  const int nt = bx & 15;
  const int me = cnt[e];
  const int m0 = mt * 128;
  if (m0 >= me) return;
  const int n0 = nt * 128;
  const int tid = threadIdx.x;

  __shared__ bf16 Hs[128][40];
  __shared__ int toks[128];
  __shared__ float tws[128];

  if (tid < 128) {
    int m = m0 + tid;
    bool v = m < me;
    toks[tid] = v ? ptok[e * T_TOK + m] : 0;
    tws[tid] = v ? pw[e * T_TOK + m] : 0.f;
  }

  const int off_e = off[e];
  const int r1 = tid >> 2, k1 = (tid & 3) * 8;
  const int r2 = r1 + 64;
  const bf16* hp1 = hact + (size_t)(off_e + m0 + r1) * F_DIM + k1;
  const bf16* hp2 = hact + (size_t)(off_e + m0 + r2) * F_DIM + k1;

  const int wave = tid >> 6, lane = tid & 63;
  const int wr = wave >> 1, wc = wave & 1;
  const int lrow = lane & 15, lkq = (lane >> 4) * 8;

  // per-lane weight base: row lkq, col n0 + wc*64 + lrow
  const float* wp = Wd + (size_t)e * F_DIM * H_DIM + (size_t)lkq * H_DIM + n0 + wc * 64 + lrow;

  f32x4 acc[4][4] = {};

  for (int f0 = 0; f0 < F_DIM; f0 += 32) {
    bf16x8 h1 = *(const bf16x8*)(hp1 + f0);
    bf16x8 h2 = *(const bf16x8*)(hp2 + f0);
    bf16x8 bfr[4];
#pragma unroll
    for (int c = 0; c < 4; ++c) {
      const float* wpc = wp + (size_t)f0 * H_DIM + c * 16;
#pragma unroll
      for (int i = 0; i < 8; ++i)
        bfr[c][i] = (bf16)wpc[(size_t)i * H_DIM];
    }
    __syncthreads();
    *(bf16x8*)&Hs[r1][k1] = h1;
    *(bf16x8*)&Hs[r2][k1] = h2;
    __syncthreads();
    bf16x8 af[4];
#pragma unroll
    for (int r = 0; r < 4; ++r)
      af[r] = *(const bf16x8*)&Hs[wr * 64 + r * 16 + lrow][lkq];
#pragma unroll
    for (int r = 0; r < 4; ++r)
#pragma unroll
      for (int c = 0; c < 4; ++c)
        acc[r][c] = __builtin_amdgcn_mfma_f32_16x16x32_bf16(af[r], bfr[c], acc[r][c], 0, 0, 0);
  }

#pragma unroll
  for (int r = 0; r < 4; ++r)
#pragma unroll
    for (int j = 0; j < 4; ++j) {
      int lm = wr * 64 + r * 16 + (lane >> 4) * 4 + j;
      if (m0 + lm < me) {
        int t = toks[lm];
        float w = tws[lm];
        float* orow = out + (size_t)t * H_DIM + n0 + wc * 64 + lrow;
#pragma unroll
        for (int c = 0; c < 4; ++c)
          atomicAdd(orow + c * 16, w * acc[r][c][j]);
      }
    }
}

// ---------------------------------------------------------------------------
extern "C" void kernel_launch(void* const* d_in, const int* in_sizes, int n_in,
                              void* d_out, int out_size, void* d_ws, size_t ws_size,
                              hipStream_t stream) {
  const float* x = (const float*)d_in[0];   // [T,H] fp32
  const float* wg = (const float*)d_in[1];  // [H,E]
  const float* Wg = (const float*)d_in[2];  // [E,H,F]
  const float* Wu = (const float*)d_in[3];  // [E,H,F]
  const float* Wd = (const float*)d_in[4];  // [E,F,H]

  float* out = (float*)d_out;                    // [T,H]
  float* logits = out + (size_t)T_TOK * H_DIM;   // [T,E]

  // workspace layout: ~51 MB total (< 65 MB proven safe in round 0)
  char* p = (char*)d_ws;
  int* cnt = (int*)p;                 p += 64;
  int* off = (int*)p;                 p += 64;
  int* ptok = (int*)p;                p += (size_t)E_NUM * T_TOK * 4;
  float* pw = (float*)p;              p += (size_t)E_NUM * T_TOK * 4;
  bf16* xb = (bf16*)p;                p += (size_t)T_TOK * H_DIM * 2;
  bf16* hact = (bf16*)p;              p += (size_t)(4 * T_TOK + 128) * F_DIM * 2;

  hipMemsetAsync(cnt, 0, E_NUM * sizeof(int), stream);
  hipLaunchKernelGGL(convert_x_kernel, dim3(T_TOK * H_DIM / 4 / 256), dim3(256), 0, stream,
                     x, xb, T_TOK * H_DIM / 4);
  hipLaunchKernelGGL(router_kernel, dim3(T_TOK), dim3(256), 0, stream,
                     x, wg, out, logits, cnt, ptok, pw);
  hipLaunchKernelGGL(prefix_kernel, dim3(1), dim3(64), 0, stream, cnt, off);
  hipLaunchKernelGGL(gateup_mfma_kernel, dim3(E_NUM * 32 * 16), dim3(256), 0, stream,
                     xb, Wg, Wu, cnt, off, ptok, hact);
  hipLaunchKernelGGL(down_mfma_kernel, dim3(E_NUM * 32 * 16), dim3(256), 0, stream,
                     hact, Wd, cnt, off, ptok, pw, out);
}